// Round 1
// baseline (256.430 us; speedup 1.0000x reference)
//
#include <hip/hip_runtime.h>
#include <stdint.h>

typedef unsigned short u16;
typedef __bf16 bf16x8 __attribute__((ext_vector_type(8)));
typedef float f32x4 __attribute__((ext_vector_type(4)));

#define CB   2
#define CLQ  2048
#define CLK  2048
#define CHID 1024
#define CNH  16
#define CHD  64

__device__ __forceinline__ u16 f2bf(float x) {
  union { float f; uint32_t u; } c; c.f = x;
  uint32_t r = c.u + 0x7FFFu + ((c.u >> 16) & 1u);
  return (u16)(r >> 16);
}

// ---------------- segment positions (per batch row) ----------------
// Computes _subseq_positions + distance gather generically on device.
__global__ __launch_bounds__(256) void pos_seg_kernel(
    const int* __restrict__ lengths, const float* __restrict__ dists,
    float* __restrict__ pos, float* __restrict__ maskv, float* __restrict__ distout,
    int L, int isKV)
{
  __shared__ int bnd[2048];
  __shared__ int part[256];
  const int b = blockIdx.x, tid = threadIdx.x;
  const int* len = lengths + (size_t)b * L;
  int loc[8];
  const int base = tid * 8;
  int s = 0;
#pragma unroll
  for (int i = 0; i < 8; i++) { loc[i] = len[base + i]; s += loc[i]; }
  part[tid] = s;
  __syncthreads();
  for (int off = 1; off < 256; off <<= 1) {
    int v = part[tid];
    int add = (tid >= off) ? part[tid - off] : 0;
    __syncthreads();
    part[tid] = v + add;
    __syncthreads();
  }
  int run = (tid > 0) ? part[tid - 1] : 0;
#pragma unroll
  for (int i = 0; i < 8; i++) { run += loc[i]; bnd[base + i] = run; }
  __syncthreads();
  const int total = bnd[L - 1];
  for (int t = tid; t < L; t += 256) {
    int lo = 0, hi = L;
    while (lo < hi) { int mid = (lo + hi) >> 1; if (bnd[mid] <= t) lo = mid + 1; else hi = mid; }
    int seg = lo < L - 1 ? lo : L - 1;
    int start = bnd[seg] - len[seg];
    bool valid = t < total;
    pos[(size_t)b * L + t] = valid ? (float)(t - start) : 0.0f;
    if (isKV) {
      maskv[(size_t)b * L + t] = valid ? 0.0f : -1e9f;
      distout[(size_t)b * L + t] = valid ? dists[(size_t)b * L + seg] : 0.0f;
    } else {
      maskv[(size_t)b * L + t] = valid ? 1.0f : 0.0f;
    }
  }
}

// ---------------- fp32 -> bf16 elementwise ----------------
__global__ __launch_bounds__(256) void cvt_kernel(const float* __restrict__ in,
                                                  u16* __restrict__ out, int n)
{
  int i = (blockIdx.x * 256 + threadIdx.x) * 4;
  if (i < n) {
    float4 v = *(const float4*)(in + i);
    ushort4 o;
    o.x = f2bf(v.x); o.y = f2bf(v.y); o.z = f2bf(v.z); o.w = f2bf(v.w);
    *(ushort4*)(out + i) = o;
  }
}

// ---------------- weight transpose + bf16: W[K][N] -> WT[N][K] ----------------
__global__ __launch_bounds__(256) void wtrans_kernel(const float* __restrict__ W,
                                                     u16* __restrict__ WT, int K, int N)
{
  __shared__ float t[64][65];
  const int nb = blockIdx.x * 64, kb = blockIdx.y * 64;
  const int tx = threadIdx.x & 63, ty = threadIdx.x >> 6;
#pragma unroll
  for (int i = 0; i < 16; i++) {
    int r = i * 4 + ty;
    t[r][tx] = W[(size_t)(kb + r) * N + nb + tx];
  }
  __syncthreads();
#pragma unroll
  for (int i = 0; i < 16; i++) {
    int r = i * 4 + ty;
    WT[(size_t)(nb + r) * K + kb + tx] = f2bf(t[tx][r]);
  }
}

// ---------------- MFMA GEMM: C[M,N] = A[M,K] @ W (W given as WT[N][K]) ----------------
// MODE 0: qproj  -> (+bq)*0.125, RoPE(pos_q), write q_rot [B,NH,LQ,HD] bf16
// MODE 1: kvproj -> cols<1024: (+bkv) RoPE(pos_k)+dist_emb -> k_rot [B,NH,LK,HD] bf16
//                   cols>=1024: (+bkv) -> v transposed [B,NH,HD,LK] bf16
// MODE 2: oproj  -> (+bo) -> fp32 out [M,N]
template<int MODE>
__global__ __launch_bounds__(256) void gemm_kernel(
    const u16* __restrict__ A, const u16* __restrict__ WT, const float* __restrict__ bias,
    int M, int N, int K,
    const float* __restrict__ pos, const float* __restrict__ dist,
    u16* __restrict__ outA, u16* __restrict__ outB, float* __restrict__ outF)
{
  __shared__ union {
    struct { u16 As[128 * 40]; u16 Bs[128 * 40]; } st;  // padded rows: 32+8 elems
    u16 tr[4][64 * 72];                                 // epilogue V-transpose buffers
  } sm;
  const int rowbase = blockIdx.y * 128;
  const int colbase = blockIdx.x * 128;
  const int tid = threadIdx.x;
  const int lane = tid & 63, wv = tid >> 6;
  const int wr = wv >> 1, wc = wv & 1;
  const int l15 = lane & 15, l4 = lane >> 4;
  f32x4 acc[4][4] = {};
  for (int kt = 0; kt < K; kt += 32) {
    __syncthreads();
#pragma unroll
    for (int i = 0; i < 2; i++) {
      int c = tid + i * 256;        // 512 chunks of 8 bf16
      int r = c >> 2, o = (c & 3) * 8;
      *(bf16x8*)&sm.st.As[r * 40 + o] = *(const bf16x8*)(A + (size_t)(rowbase + r) * K + kt + o);
      *(bf16x8*)&sm.st.Bs[r * 40 + o] = *(const bf16x8*)(WT + (size_t)(colbase + r) * K + kt + o);
    }
    __syncthreads();
    bf16x8 af[4], bfr[4];
#pragma unroll
    for (int m = 0; m < 4; m++)
      af[m] = *(const bf16x8*)&sm.st.As[(wr * 64 + m * 16 + l15) * 40 + l4 * 8];
#pragma unroll
    for (int n = 0; n < 4; n++)
      bfr[n] = *(const bf16x8*)&sm.st.Bs[(wc * 64 + n * 16 + l15) * 40 + l4 * 8];
#pragma unroll
    for (int m = 0; m < 4; m++)
#pragma unroll
      for (int n = 0; n < 4; n++)
        acc[m][n] = __builtin_amdgcn_mfma_f32_16x16x32_bf16(af[m], bfr[n], acc[m][n], 0, 0, 0);
  }
  __syncthreads();

  if constexpr (MODE == 2) {
#pragma unroll
    for (int n = 0; n < 4; n++) {
      float bv = bias[colbase + wc * 64 + n * 16 + l15];
#pragma unroll
      for (int m = 0; m < 4; m++)
#pragma unroll
        for (int r = 0; r < 4; r++) {
          int grow = rowbase + wr * 64 + m * 16 + l4 * 4 + r;
          outF[(size_t)grow * N + colbase + wc * 64 + n * 16 + l15] = acc[m][n][r] + bv;
        }
    }
  } else if constexpr (MODE == 0) {
    const int b = rowbase >> 11;
    const int h = (colbase + wc * 64) >> 6;
    const float if0 = __powf(10000.0f, -(float)l15 / 32.0f);
    const float if1 = __powf(10000.0f, -(float)(16 + l15) / 32.0f);
    const float b0 = bias[colbase + wc * 64 + l15];
    const float b1 = bias[colbase + wc * 64 + 16 + l15];
    const float b2 = bias[colbase + wc * 64 + 32 + l15];
    const float b3 = bias[colbase + wc * 64 + 48 + l15];
#pragma unroll
    for (int m = 0; m < 4; m++) {
#pragma unroll
      for (int r = 0; r < 4; r++) {
        int grow = rowbase + wr * 64 + m * 16 + l4 * 4 + r;
        int tok = grow & 2047;
        float pv = pos[grow];
        float s0, c0, s1, c1;
        __sincosf(pv * if0, &s0, &c0);
        __sincosf(pv * if1, &s1, &c1);
        float x0 = (acc[m][0][r] + b0) * 0.125f;
        float x1 = (acc[m][1][r] + b1) * 0.125f;
        float x2 = (acc[m][2][r] + b2) * 0.125f;
        float x3 = (acc[m][3][r] + b3) * 0.125f;
        size_t ob = (((size_t)b * CNH + h) * CLQ + tok) * CHD;
        outA[ob + l15]      = f2bf(x0 * c0 - x2 * s0);
        outA[ob + 32 + l15] = f2bf(x2 * c0 + x0 * s0);
        outA[ob + 16 + l15] = f2bf(x1 * c1 - x3 * s1);
        outA[ob + 48 + l15] = f2bf(x3 * c1 + x1 * s1);
      }
    }
  } else {  // MODE 1
    const int b = rowbase >> 11;
    if (colbase < CHID) {   // K half
      const int h = (colbase + wc * 64) >> 6;
      const float if0 = __powf(10000.0f, -(float)l15 / 32.0f);
      const float if1 = __powf(10000.0f, -(float)(16 + l15) / 32.0f);
      // geomspace(1e-5, 0.25, 32)[j] = exp(ln 1e-5 + j*(ln .25 - ln 1e-5)/31)
      const float df0 = __expf(-11.5129254f + 0.32666551f * (float)l15);
      const float df1 = __expf(-11.5129254f + 0.32666551f * (float)(16 + l15));
      const float b0 = bias[colbase + wc * 64 + l15];
      const float b1 = bias[colbase + wc * 64 + 16 + l15];
      const float b2 = bias[colbase + wc * 64 + 32 + l15];
      const float b3 = bias[colbase + wc * 64 + 48 + l15];
#pragma unroll
      for (int m = 0; m < 4; m++) {
#pragma unroll
        for (int r = 0; r < 4; r++) {
          int grow = rowbase + wr * 64 + m * 16 + l4 * 4 + r;
          int tok = grow & 2047;
          float pv = pos[grow];
          float dv = dist[grow];
          float s0, c0, s1, c1, ds0, dc0, ds1, dc1;
          __sincosf(pv * if0, &s0, &c0);
          __sincosf(pv * if1, &s1, &c1);
          __sincosf(dv * df0, &ds0, &dc0);
          __sincosf(dv * df1, &ds1, &dc1);
          float x0 = acc[m][0][r] + b0;
          float x1 = acc[m][1][r] + b1;
          float x2 = acc[m][2][r] + b2;
          float x3 = acc[m][3][r] + b3;
          size_t ob = (((size_t)b * CNH + h) * CLK + tok) * CHD;
          outA[ob + l15]      = f2bf(x0 * c0 - x2 * s0 + dc0);
          outA[ob + 32 + l15] = f2bf(x2 * c0 + x0 * s0 + ds0);
          outA[ob + 16 + l15] = f2bf(x1 * c1 - x3 * s1 + dc1);
          outA[ob + 48 + l15] = f2bf(x3 * c1 + x1 * s1 + ds1);
        }
      }
    } else {                // V half -> write transposed [B,NH,HD,LK]
      const int h = (colbase + wc * 64 - CHID) >> 6;
      const int tokb = (rowbase & 2047) + wr * 64;
      u16* T = sm.tr[wv];
#pragma unroll
      for (int n = 0; n < 4; n++) {
        float bv = bias[colbase + wc * 64 + n * 16 + l15];
#pragma unroll
        for (int m = 0; m < 4; m++)
#pragma unroll
          for (int r = 0; r < 4; r++)
            T[(n * 16 + l15) * 72 + m * 16 + l4 * 4 + r] = f2bf(acc[m][n][r] + bv);
      }
#pragma unroll
      for (int p = 0; p < 8; p++) {
        int c = p * 64 + lane;
        int hd = c >> 3, to = (c & 7) * 8;
        *(bf16x8*)(outB + (((size_t)b * CNH + h) * CHD + hd) * CLK + tokb + to) =
            *(const bf16x8*)&T[hd * 72 + to];
      }
    }
  }
}

// ---------------- flash attention: per (q-tile 64, head, batch) ----------------
__global__ __launch_bounds__(256) void attn_kernel(
    const u16* __restrict__ qr, const u16* __restrict__ kr, const u16* __restrict__ vt,
    const float* __restrict__ kbias, const float* __restrict__ validq,
    u16* __restrict__ aout)
{
  __shared__ u16 Ks[64 * 72];       // [tok][hd], padded
  __shared__ u16 Vs[64 * 72];       // [hd][tok], padded (V pre-transposed in global)
  __shared__ u16 Ps[4][16 * 72];    // per-wave P re-fragment buffer
  __shared__ float KBs[64];
  const int qb = blockIdx.x * 64;
  const int h = blockIdx.y, b = blockIdx.z;
  const int tid = threadIdx.x, lane = tid & 63, wv = tid >> 6;
  const int l15 = lane & 15, l4 = lane >> 4;
  const u16* qg = qr + ((((size_t)b * CNH + h) * CLQ) + qb + wv * 16) * CHD;
  const bf16x8 qa0 = *(const bf16x8*)(qg + l15 * CHD + l4 * 8);
  const bf16x8 qa1 = *(const bf16x8*)(qg + l15 * CHD + 32 + l4 * 8);
  const u16* kg = kr + (((size_t)b * CNH + h) * CLK) * CHD;
  const u16* vg = vt + (((size_t)b * CNH + h) * CHD) * CLK;
  f32x4 accO[4] = {};
  float mrow[4] = {-1e30f, -1e30f, -1e30f, -1e30f};
  float lrow[4] = {0.f, 0.f, 0.f, 0.f};
  for (int kt = 0; kt < CLK; kt += 64) {
#pragma unroll
    for (int i = 0; i < 2; i++) {
      int c = tid + i * 256;
      int r = c >> 3, o = (c & 7) * 8;
      *(bf16x8*)&Ks[r * 72 + o] = *(const bf16x8*)(kg + (size_t)(kt + r) * CHD + o);
      *(bf16x8*)&Vs[r * 72 + o] = *(const bf16x8*)(vg + (size_t)r * CLK + kt + o);
    }
    if (tid < 64) KBs[tid] = kbias[(size_t)b * CLK + kt + tid];
    __syncthreads();
    f32x4 s[4];
#pragma unroll
    for (int c = 0; c < 4; c++) {
      bf16x8 k0 = *(const bf16x8*)&Ks[(c * 16 + l15) * 72 + l4 * 8];
      bf16x8 k1 = *(const bf16x8*)&Ks[(c * 16 + l15) * 72 + 32 + l4 * 8];
      f32x4 z = {};
      z = __builtin_amdgcn_mfma_f32_16x16x32_bf16(qa0, k0, z, 0, 0, 0);
      z = __builtin_amdgcn_mfma_f32_16x16x32_bf16(qa1, k1, z, 0, 0, 0);
      float bv = KBs[c * 16 + l15];
#pragma unroll
      for (int r = 0; r < 4; r++) s[c][r] = z[r] + bv;
    }
    float tm[4];
#pragma unroll
    for (int r = 0; r < 4; r++)
      tm[r] = fmaxf(fmaxf(s[0][r], s[1][r]), fmaxf(s[2][r], s[3][r]));
#pragma unroll
    for (int off = 1; off < 16; off <<= 1)
#pragma unroll
      for (int r = 0; r < 4; r++)
        tm[r] = fmaxf(tm[r], __shfl_xor(tm[r], off, 64));
#pragma unroll
    for (int r = 0; r < 4; r++) {
      float mn = fmaxf(mrow[r], tm[r]);
      float sc = __expf(mrow[r] - mn);
      mrow[r] = mn;
      lrow[r] *= sc;
#pragma unroll
      for (int c2 = 0; c2 < 4; c2++) accO[c2][r] *= sc;
    }
    u16* Pw = Ps[wv];
    float pl[4] = {0.f, 0.f, 0.f, 0.f};
#pragma unroll
    for (int c = 0; c < 4; c++)
#pragma unroll
      for (int r = 0; r < 4; r++) {
        float p = __expf(s[c][r] - mrow[r]);
        pl[r] += p;
        Pw[(l4 * 4 + r) * 72 + c * 16 + l15] = f2bf(p);
      }
#pragma unroll
    for (int r = 0; r < 4; r++) {
#pragma unroll
      for (int off = 1; off < 16; off <<= 1) pl[r] += __shfl_xor(pl[r], off, 64);
      lrow[r] += pl[r];
    }
    bf16x8 pa0 = *(const bf16x8*)&Pw[l15 * 72 + l4 * 8];
    bf16x8 pa1 = *(const bf16x8*)&Pw[l15 * 72 + 32 + l4 * 8];
#pragma unroll
    for (int c2 = 0; c2 < 4; c2++) {
      bf16x8 v0 = *(const bf16x8*)&Vs[(c2 * 16 + l15) * 72 + l4 * 8];
      bf16x8 v1 = *(const bf16x8*)&Vs[(c2 * 16 + l15) * 72 + 32 + l4 * 8];
      accO[c2] = __builtin_amdgcn_mfma_f32_16x16x32_bf16(pa0, v0, accO[c2], 0, 0, 0);
      accO[c2] = __builtin_amdgcn_mfma_f32_16x16x32_bf16(pa1, v1, accO[c2], 0, 0, 0);
    }
    __syncthreads();
  }
#pragma unroll
  for (int r = 0; r < 4; r++) {
    int grow = qb + wv * 16 + l4 * 4 + r;
    float w = validq[(size_t)b * CLQ + grow] / lrow[r];
    size_t ob = ((size_t)b * CLQ + grow) * CHID + h * CHD;
#pragma unroll
    for (int c2 = 0; c2 < 4; c2++)
      aout[ob + c2 * 16 + l15] = f2bf(accO[c2][r] * w);
  }
}

extern "C" void kernel_launch(void* const* d_in, const int* in_sizes, int n_in,
                              void* d_out, int out_size, void* d_ws, size_t ws_size,
                              hipStream_t stream)
{
  const float* q_states  = (const float*)d_in[0];
  const float* kv_states = (const float*)d_in[1];
  const float* dists     = (const float*)d_in[2];
  const int*   mq        = (const int*)d_in[3];
  const int*   mkv       = (const int*)d_in[4];
  const float* Wq        = (const float*)d_in[5];
  const float* bq        = (const float*)d_in[6];
  const float* Wkv       = (const float*)d_in[7];
  const float* bkv       = (const float*)d_in[8];
  const float* Wo        = (const float*)d_in[9];
  const float* bo        = (const float*)d_in[10];
  float* out = (float*)d_out;

  char* w = (char*)d_ws;
  auto alloc = [&](size_t bytes) {
    char* p = w;
    w += (bytes + 255) & ~(size_t)255;
    return p;
  };
  u16* WqT  = (u16*)alloc((size_t)1024 * 1024 * 2);
  u16* WkvT = (u16*)alloc((size_t)2048 * 1024 * 2);
  u16* WoT  = (u16*)alloc((size_t)1024 * 1024 * 2);
  u16* QS   = (u16*)alloc((size_t)4096 * 1024 * 2);
  u16* KVS  = (u16*)alloc((size_t)4096 * 1024 * 2);
  u16* QROT = (u16*)alloc((size_t)4096 * 1024 * 2);
  u16* KROT = (u16*)alloc((size_t)4096 * 1024 * 2);
  u16* VT   = (u16*)alloc((size_t)4096 * 1024 * 2);
  u16* AOUT = (u16*)alloc((size_t)4096 * 1024 * 2);
  float* posq  = (float*)alloc(4096 * 4);
  float* vq    = (float*)alloc(4096 * 4);
  float* posk  = (float*)alloc(4096 * 4);
  float* kbias = (float*)alloc(4096 * 4);
  float* dtok  = (float*)alloc(4096 * 4);

  wtrans_kernel<<<dim3(16, 16), 256, 0, stream>>>(Wq, WqT, 1024, 1024);
  wtrans_kernel<<<dim3(32, 16), 256, 0, stream>>>(Wkv, WkvT, 1024, 2048);
  wtrans_kernel<<<dim3(16, 16), 256, 0, stream>>>(Wo, WoT, 1024, 1024);
  cvt_kernel<<<4096, 256, 0, stream>>>(q_states, QS, 4096 * 1024);
  cvt_kernel<<<4096, 256, 0, stream>>>(kv_states, KVS, 4096 * 1024);
  pos_seg_kernel<<<2, 256, 0, stream>>>(mq, nullptr, posq, vq, nullptr, 2048, 0);
  pos_seg_kernel<<<2, 256, 0, stream>>>(mkv, dists, posk, kbias, dtok, 2048, 1);

  gemm_kernel<0><<<dim3(8, 32), 256, 0, stream>>>(QS, WqT, bq, 4096, 1024, 1024,
                                                  posq, nullptr, QROT, nullptr, nullptr);
  gemm_kernel<1><<<dim3(16, 32), 256, 0, stream>>>(KVS, WkvT, bkv, 4096, 2048, 1024,
                                                   posk, dtok, KROT, VT, nullptr);
  attn_kernel<<<dim3(32, 16, 2), 256, 0, stream>>>(QROT, KROT, VT, kbias, vq, AOUT);
  gemm_kernel<2><<<dim3(8, 32), 256, 0, stream>>>(AOUT, WoT, bo, 4096, 1024, 1024,
                                                  nullptr, nullptr, nullptr, nullptr, out);
}

// Round 5
// 197.817 us; speedup vs baseline: 1.2963x; 1.2963x over previous
//
#include <hip/hip_runtime.h>
#include <stdint.h>

typedef unsigned short u16;
typedef __bf16 bf16x8 __attribute__((ext_vector_type(8)));
typedef float f32x4 __attribute__((ext_vector_type(4)));

#define CB   2
#define CLQ  2048
#define CLK  2048
#define CHID 1024
#define CNH  16
#define CHD  64

__device__ __forceinline__ u16 f2bf(float x) {
  union { float f; uint32_t u; } c; c.f = x;
  uint32_t r = c.u + 0x7FFFu + ((c.u >> 16) & 1u);
  return (u16)(r >> 16);
}

__device__ __forceinline__ uint32_t cvtpk(float lo, float hi) {
  uint32_t r;
  asm("v_cvt_pk_bf16_f32 %0, %1, %2" : "=v"(r) : "v"(lo), "v"(hi));
  return r;
}

typedef __attribute__((address_space(3))) uint32_t lds_u32;
typedef const __attribute__((address_space(1))) uint32_t glb_u32;
__device__ __forceinline__ void gload16(const void* g, void* l) {
  __builtin_amdgcn_global_load_lds((glb_u32*)g, (lds_u32*)l, 16, 0, 0);
}

// ---------------- segment positions (per batch row) ----------------
__global__ __launch_bounds__(256) void pos_seg_kernel(
    const int* __restrict__ lengths, const float* __restrict__ dists,
    float* __restrict__ pos, float* __restrict__ maskv, float* __restrict__ distout,
    int L, int isKV)
{
  __shared__ int bnd[2048];
  __shared__ int part[256];
  const int b = blockIdx.x, tid = threadIdx.x;
  const int* len = lengths + (size_t)b * L;
  int loc[8];
  const int base = tid * 8;
  int s = 0;
#pragma unroll
  for (int i = 0; i < 8; i++) { loc[i] = len[base + i]; s += loc[i]; }
  part[tid] = s;
  __syncthreads();
  for (int off = 1; off < 256; off <<= 1) {
    int v = part[tid];
    int add = (tid >= off) ? part[tid - off] : 0;
    __syncthreads();
    part[tid] = v + add;
    __syncthreads();
  }
  int run = (tid > 0) ? part[tid - 1] : 0;
#pragma unroll
  for (int i = 0; i < 8; i++) { run += loc[i]; bnd[base + i] = run; }
  __syncthreads();
  const int total = bnd[L - 1];
  for (int t = tid; t < L; t += 256) {
    int lo = 0, hi = L;
    while (lo < hi) { int mid = (lo + hi) >> 1; if (bnd[mid] <= t) lo = mid + 1; else hi = mid; }
    int seg = lo < L - 1 ? lo : L - 1;
    int start = bnd[seg] - len[seg];
    bool valid = t < total;
    pos[(size_t)b * L + t] = valid ? (float)(t - start) : 0.0f;
    if (isKV) {
      maskv[(size_t)b * L + t] = valid ? 0.0f : -1e9f;
      distout[(size_t)b * L + t] = valid ? dists[(size_t)b * L + seg] : 0.0f;
    } else {
      maskv[(size_t)b * L + t] = valid ? 1.0f : 0.0f;
    }
  }
}

// ---------------- fp32 -> bf16 elementwise ----------------
__global__ __launch_bounds__(256) void cvt_kernel(const float* __restrict__ in,
                                                  u16* __restrict__ out, int n)
{
  int i = (blockIdx.x * 256 + threadIdx.x) * 4;
  if (i < n) {
    float4 v = *(const float4*)(in + i);
    ushort4 o;
    o.x = f2bf(v.x); o.y = f2bf(v.y); o.z = f2bf(v.z); o.w = f2bf(v.w);
    *(ushort4*)(out + i) = o;
  }
}

// ---------------- weight transpose + bf16: W[K][N] -> WT[N][K] ----------------
__global__ __launch_bounds__(256) void wtrans_kernel(const float* __restrict__ W,
                                                     u16* __restrict__ WT, int K, int N)
{
  __shared__ float t[64][65];
  const int nb = blockIdx.x * 64, kb = blockIdx.y * 64;
  const int tx = threadIdx.x & 63, ty = threadIdx.x >> 6;
#pragma unroll
  for (int i = 0; i < 16; i++) {
    int r = i * 4 + ty;
    t[r][tx] = W[(size_t)(kb + r) * N + nb + tx];
  }
  __syncthreads();
#pragma unroll
  for (int i = 0; i < 16; i++) {
    int r = i * 4 + ty;
    WT[(size_t)(nb + r) * K + kb + tx] = f2bf(t[tx][r]);
  }
}

// ---------------- MFMA GEMM: C[M,N] = A[M,K] @ W (W given as WT[N][K]) ----------------
// gload_lds staging, linear LDS [128][32] with chunk^=(row&3) swizzle.
template<int MODE>
__global__ __launch_bounds__(256) void gemm_kernel(
    const u16* __restrict__ A, const u16* __restrict__ WT, const float* __restrict__ bias,
    int M, int N, int K,
    const float* __restrict__ pos, const float* __restrict__ dist,
    u16* __restrict__ outA, u16* __restrict__ outB, float* __restrict__ outF)
{
  __shared__ __align__(16) union {
    struct { u16 As[128 * 32]; u16 Bs[128 * 32]; } st;
    u16 tr[4][64 * 72];                 // epilogue V-transpose buffers
  } sm;
  const int rowbase = blockIdx.y * 128;
  const int colbase = blockIdx.x * 128;
  const int tid = threadIdx.x;
  const int lane = tid & 63, wv = tid >> 6;
  const int wr = wv >> 1, wc = wv & 1;
  const int l15 = lane & 15, l4 = lane >> 4;
  const int sr = lane >> 2;                 // staging row-within-region (0..15)
  const int sj = (lane & 3) ^ (sr & 3);     // swizzled source chunk
  f32x4 acc[4][4] = {};
  for (int kt = 0; kt < K; kt += 32) {
    __syncthreads();
#pragma unroll
    for (int i = 0; i < 2; i++) {
      int r = (wv * 2 + i) * 16 + sr;
      gload16(A  + (size_t)(rowbase + r) * K + kt + sj * 8, &sm.st.As[(wv*2+i)*512]);
      gload16(WT + (size_t)(colbase + r) * K + kt + sj * 8, &sm.st.Bs[(wv*2+i)*512]);
    }
    __syncthreads();
    bf16x8 af[4], bfr[4];
    const int fsw = (l15 & 3);
#pragma unroll
    for (int m = 0; m < 4; m++)
      af[m] = *(const bf16x8*)&sm.st.As[(wr * 64 + m * 16 + l15) * 32 + ((l4 ^ fsw) * 8)];
#pragma unroll
    for (int n = 0; n < 4; n++)
      bfr[n] = *(const bf16x8*)&sm.st.Bs[(wc * 64 + n * 16 + l15) * 32 + ((l4 ^ fsw) * 8)];
#pragma unroll
    for (int m = 0; m < 4; m++)
#pragma unroll
      for (int n = 0; n < 4; n++)
        acc[m][n] = __builtin_amdgcn_mfma_f32_16x16x32_bf16(af[m], bfr[n], acc[m][n], 0, 0, 0);
  }
  __syncthreads();

  if constexpr (MODE == 2) {
#pragma unroll
    for (int n = 0; n < 4; n++) {
      float bv = bias[colbase + wc * 64 + n * 16 + l15];
#pragma unroll
      for (int m = 0; m < 4; m++)
#pragma unroll
        for (int r = 0; r < 4; r++) {
          int grow = rowbase + wr * 64 + m * 16 + l4 * 4 + r;
          outF[(size_t)grow * N + colbase + wc * 64 + n * 16 + l15] = acc[m][n][r] + bv;
        }
    }
  } else if constexpr (MODE == 0) {
    const int b = rowbase >> 11;
    const int h = (colbase + wc * 64) >> 6;
    const float if0 = __powf(10000.0f, -(float)l15 / 32.0f);
    const float if1 = __powf(10000.0f, -(float)(16 + l15) / 32.0f);
    const float b0 = bias[colbase + wc * 64 + l15];
    const float b1 = bias[colbase + wc * 64 + 16 + l15];
    const float b2 = bias[colbase + wc * 64 + 32 + l15];
    const float b3 = bias[colbase + wc * 64 + 48 + l15];
#pragma unroll
    for (int m = 0; m < 4; m++) {
#pragma unroll
      for (int r = 0; r < 4; r++) {
        int grow = rowbase + wr * 64 + m * 16 + l4 * 4 + r;
        int tok = grow & 2047;
        float pv = pos[grow];
        float s0, c0, s1, c1;
        __sincosf(pv * if0, &s0, &c0);
        __sincosf(pv * if1, &s1, &c1);
        float x0 = (acc[m][0][r] + b0) * 0.125f;
        float x1 = (acc[m][1][r] + b1) * 0.125f;
        float x2 = (acc[m][2][r] + b2) * 0.125f;
        float x3 = (acc[m][3][r] + b3) * 0.125f;
        size_t ob = (((size_t)b * CNH + h) * CLQ + tok) * CHD;
        outA[ob + l15]      = f2bf(x0 * c0 - x2 * s0);
        outA[ob + 32 + l15] = f2bf(x2 * c0 + x0 * s0);
        outA[ob + 16 + l15] = f2bf(x1 * c1 - x3 * s1);
        outA[ob + 48 + l15] = f2bf(x3 * c1 + x1 * s1);
      }
    }
  } else {  // MODE 1
    const int b = rowbase >> 11;
    if (colbase < CHID) {   // K half
      const int h = (colbase + wc * 64) >> 6;
      const float if0 = __powf(10000.0f, -(float)l15 / 32.0f);
      const float if1 = __powf(10000.0f, -(float)(16 + l15) / 32.0f);
      const float df0 = __expf(-11.5129254f + 0.32666551f * (float)l15);
      const float df1 = __expf(-11.5129254f + 0.32666551f * (float)(16 + l15));
      const float b0 = bias[colbase + wc * 64 + l15];
      const float b1 = bias[colbase + wc * 64 + 16 + l15];
      const float b2 = bias[colbase + wc * 64 + 32 + l15];
      const float b3 = bias[colbase + wc * 64 + 48 + l15];
#pragma unroll
      for (int m = 0; m < 4; m++) {
#pragma unroll
        for (int r = 0; r < 4; r++) {
          int grow = rowbase + wr * 64 + m * 16 + l4 * 4 + r;
          int tok = grow & 2047;
          float pv = pos[grow];
          float dv = dist[grow];
          float s0, c0, s1, c1, ds0, dc0, ds1, dc1;
          __sincosf(pv * if0, &s0, &c0);
          __sincosf(pv * if1, &s1, &c1);
          __sincosf(dv * df0, &ds0, &dc0);
          __sincosf(dv * df1, &ds1, &dc1);
          float x0 = acc[m][0][r] + b0;
          float x1 = acc[m][1][r] + b1;
          float x2 = acc[m][2][r] + b2;
          float x3 = acc[m][3][r] + b3;
          size_t ob = (((size_t)b * CNH + h) * CLK + tok) * CHD;
          outA[ob + l15]      = f2bf(x0 * c0 - x2 * s0 + dc0);
          outA[ob + 32 + l15] = f2bf(x2 * c0 + x0 * s0 + ds0);
          outA[ob + 16 + l15] = f2bf(x1 * c1 - x3 * s1 + dc1);
          outA[ob + 48 + l15] = f2bf(x3 * c1 + x1 * s1 + ds1);
        }
      }
    } else {                // V half -> write transposed [B,NH,HD,LK]
      const int h = (colbase + wc * 64 - CHID) >> 6;
      const int tokb = (rowbase & 2047) + wr * 64;
      u16* T = sm.tr[wv];
#pragma unroll
      for (int n = 0; n < 4; n++) {
        float bv = bias[colbase + wc * 64 + n * 16 + l15];
#pragma unroll
        for (int m = 0; m < 4; m++)
#pragma unroll
          for (int r = 0; r < 4; r++)
            T[(n * 16 + l15) * 72 + m * 16 + l4 * 4 + r] = f2bf(acc[m][n][r] + bv);
      }
#pragma unroll
      for (int p = 0; p < 8; p++) {
        int c = p * 64 + lane;
        int hd = c >> 3, to = (c & 7) * 8;
        *(bf16x8*)(outB + (((size_t)b * CNH + h) * CHD + hd) * CLK + tokb + to) =
            *(const bf16x8*)&T[hd * 72 + to];
      }
    }
  }
}

// ---------------- flash attention, swapped-operand form ----------------
// Block: 4 waves x 32 q-rows = QBLK 128. KV tile = 64. Double-buffered LDS
// staged via global_load_lds with XOR-pre-swizzled source.
// P^T bounce: 8 kv-blocks of 256B at BIJECTIVE stride 288 (fix for R2's
// overlapping (t8&1)*32 shift which aliased blocks 1/2, 3/4, 5/6).
__global__ __launch_bounds__(256) void attn_kernel(
    const u16* __restrict__ qr, const u16* __restrict__ kr, const u16* __restrict__ vt,
    const float* __restrict__ kbias, const float* __restrict__ validq,
    u16* __restrict__ aout)
{
  __shared__ __align__(16) u16 Ks[2][64 * 64];   // [tok][hd], swizzled 128B rows
  __shared__ __align__(16) u16 Vs[2][64 * 64];   // [hd][tok], swizzled 128B rows
  __shared__ __align__(16) u16 Pb[4][1184];      // per-wave P^T B-frag buffer / epilogue bounce
  const int qb = blockIdx.x * 128;
  const int h = blockIdx.y, b = blockIdx.z;
  const int tid = threadIdx.x, lane = tid & 63, wv = tid >> 6;
  const int l15 = lane & 15, l4 = lane >> 4;
  const u16* kg = kr + ((size_t)b * CNH + h) * CLK * CHD;
  const u16* vg = vt + ((size_t)b * CNH + h) * CHD * CLK;
  const float* kb_b = kbias + (size_t)b * CLK;
  const int qrow0 = qb + wv * 32;
  const u16* qg = qr + (((size_t)b * CNH + h) * CLQ + qrow0) * CHD;

  bf16x8 qf[2][2];
#pragma unroll
  for (int m = 0; m < 2; m++)
#pragma unroll
    for (int hc = 0; hc < 2; hc++)
      qf[m][hc] = *(const bf16x8*)(qg + (m * 16 + l15) * CHD + hc * 32 + l4 * 8);

  const int srow = lane >> 3;               // 0..7 (row within 1KB region)
  const int sj = (lane & 7) ^ srow;         // swizzled source chunk
  f32x4 accO[2][4] = {};
  float mReg[2] = {-1e30f, -1e30f};
  float lReg[2] = {0.f, 0.f};

  auto stage = [&](int buf, int kt) {
#pragma unroll
    for (int i = 0; i < 2; i++) {
      int r = (wv * 2 + i) * 8 + srow;
      gload16(kg + (size_t)(kt + r) * CHD + sj * 8, &Ks[buf][(wv * 2 + i) * 512]);
      gload16(vg + (size_t)r * CLK + kt + sj * 8,   &Vs[buf][(wv * 2 + i) * 512]);
    }
  };

  stage(0, 0);
  __syncthreads();
  for (int t = 0; t < CLK / 64; t++) {
    const int cur = t & 1;
    if (t < CLK / 64 - 1) stage(cur ^ 1, (t + 1) * 64);
    const u16* Kc = Ks[cur];
    const u16* Vc = Vs[cur];
    const int fsw = l15 & 7;
    float4 kb4[4];
#pragma unroll
    for (int c = 0; c < 4; c++)
      kb4[c] = *(const float4*)(kb_b + t * 64 + c * 16 + l4 * 4);
    bf16x8 kf[4][2], vf[4][2];
#pragma unroll
    for (int c = 0; c < 4; c++)
#pragma unroll
      for (int hc = 0; hc < 2; hc++)
        kf[c][hc] = *(const bf16x8*)&Kc[(c * 16 + l15) * 64 + (((hc * 4 + l4) ^ fsw) * 8)];
#pragma unroll
    for (int hh = 0; hh < 4; hh++)
#pragma unroll
      for (int kc = 0; kc < 2; kc++)
        vf[hh][kc] = *(const bf16x8*)&Vc[(hh * 16 + l15) * 64 + (((kc * 4 + l4) ^ fsw) * 8)];
    u16* PbW = Pb[wv];
#pragma unroll
    for (int m = 0; m < 2; m++) {
      f32x4 s[4];
#pragma unroll
      for (int c = 0; c < 4; c++) {
        f32x4 z = {};
        z = __builtin_amdgcn_mfma_f32_16x16x32_bf16(kf[c][0], qf[m][0], z, 0, 0, 0);
        z = __builtin_amdgcn_mfma_f32_16x16x32_bf16(kf[c][1], qf[m][1], z, 0, 0, 0);
        const float* kbp = (const float*)&kb4[c];
#pragma unroll
        for (int r = 0; r < 4; r++) s[c][r] = z[r] + kbp[r];
      }
      float t0 = fmaxf(fmaxf(s[0][0], s[0][1]), fmaxf(s[0][2], s[0][3]));
      float t1 = fmaxf(fmaxf(s[1][0], s[1][1]), fmaxf(s[1][2], s[1][3]));
      float t2 = fmaxf(fmaxf(s[2][0], s[2][1]), fmaxf(s[2][2], s[2][3]));
      float t3 = fmaxf(fmaxf(s[3][0], s[3][1]), fmaxf(s[3][2], s[3][3]));
      float tm = fmaxf(fmaxf(t0, t1), fmaxf(t2, t3));
      tm = fmaxf(tm, __shfl_xor(tm, 16));
      tm = fmaxf(tm, __shfl_xor(tm, 32));
      if (__any(tm > mReg[m] + 8.0f)) {          // defer-max (T13)
        float mn = fmaxf(mReg[m], tm);
        float sc = __expf(mReg[m] - mn);
        mReg[m] = mn;
        lReg[m] *= sc;
#pragma unroll
        for (int hh = 0; hh < 4; hh++)
#pragma unroll
          for (int r = 0; r < 4; r++) accO[m][hh][r] *= sc;
      }
      float p[16];
#pragma unroll
      for (int c = 0; c < 4; c++)
#pragma unroll
        for (int r = 0; r < 4; r++)
          p[c * 4 + r] = __expf(s[c][r] - mReg[m]);
      lReg[m] += (((p[0] + p[1]) + (p[2] + p[3])) + ((p[4] + p[5]) + (p[6] + p[7]))) +
                 (((p[8] + p[9]) + (p[10] + p[11])) + ((p[12] + p[13]) + (p[14] + p[15])));
      // write P^T in PV B-frag order: kv-block t8 holds kv [8*t8, 8*t8+8)
      // for q=l15, at bijective stride 288B per block.
      const int wbase = 2 * (l4 & 1);
#pragma unroll
      for (int c = 0; c < 4; c++) {
        int t8 = 2 * c + (l4 >> 1);
        uint32_t off = (uint32_t)(t8 * 288 + l15 * 16);
#pragma unroll
        for (int rr = 0; rr < 2; rr++) {
          uint32_t w32 = cvtpk(p[c * 4 + 2 * rr], p[c * 4 + 2 * rr + 1]);
          *(uint32_t*)((char*)PbW + off + (wbase + rr) * 4) = w32;
        }
      }
      const bf16x8 plo = *(const bf16x8*)((const char*)PbW + l4 * 288 + l15 * 16);
      const bf16x8 phi = *(const bf16x8*)((const char*)PbW + 1152 + l4 * 288 + l15 * 16);
#pragma unroll
      for (int hh = 0; hh < 4; hh++) {
        accO[m][hh] = __builtin_amdgcn_mfma_f32_16x16x32_bf16(vf[hh][0], plo, accO[m][hh], 0, 0, 0);
        accO[m][hh] = __builtin_amdgcn_mfma_f32_16x16x32_bf16(vf[hh][1], phi, accO[m][hh], 0, 0, 0);
      }
    }
    __syncthreads();
  }

  // epilogue: normalize, bounce through LDS for coalesced stores
  u16* PbW = Pb[wv];
#pragma unroll
  for (int m = 0; m < 2; m++) {
    float lq = lReg[m];
    lq += __shfl_xor(lq, 16);
    lq += __shfl_xor(lq, 32);
    float inv = validq[(size_t)b * CLQ + qrow0 + m * 16 + l15] / lq;
#pragma unroll
    for (int hh = 0; hh < 4; hh++)
#pragma unroll
      for (int rr = 0; rr < 2; rr++) {
        uint32_t w32 = cvtpk(accO[m][hh][2 * rr] * inv, accO[m][hh][2 * rr + 1] * inv);
        *(uint32_t*)((char*)PbW + l15 * 144 + (hh * 16 + l4 * 4 + 2 * rr) * 2) = w32;
      }
#pragma unroll
    for (int i = 0; i < 2; i++) {
      int row = i * 8 + (lane >> 3), ch = lane & 7;
      bf16x8 ov = *(const bf16x8*)((const char*)PbW + row * 144 + ch * 16);
      *(bf16x8*)(aout + ((size_t)b * CLQ + qrow0 + m * 16 + row) * CHID + h * CHD + ch * 8) = ov;
    }
  }
}

extern "C" void kernel_launch(void* const* d_in, const int* in_sizes, int n_in,
                              void* d_out, int out_size, void* d_ws, size_t ws_size,
                              hipStream_t stream)
{
  const float* q_states  = (const float*)d_in[0];
  const float* kv_states = (const float*)d_in[1];
  const float* dists     = (const float*)d_in[2];
  const int*   mq        = (const int*)d_in[3];
  const int*   mkv       = (const int*)d_in[4];
  const float* Wq        = (const float*)d_in[5];
  const float* bq        = (const float*)d_in[6];
  const float* Wkv       = (const float*)d_in[7];
  const float* bkv       = (const float*)d_in[8];
  const float* Wo        = (const float*)d_in[9];
  const float* bo        = (const float*)d_in[10];
  float* out = (float*)d_out;

  char* w = (char*)d_ws;
  auto alloc = [&](size_t bytes) {
    char* p = w;
    w += (bytes + 255) & ~(size_t)255;
    return p;
  };
  u16* WqT  = (u16*)alloc((size_t)1024 * 1024 * 2);
  u16* WkvT = (u16*)alloc((size_t)2048 * 1024 * 2);
  u16* WoT  = (u16*)alloc((size_t)1024 * 1024 * 2);
  u16* QS   = (u16*)alloc((size_t)4096 * 1024 * 2);
  u16* KVS  = (u16*)alloc((size_t)4096 * 1024 * 2);
  u16* QROT = (u16*)alloc((size_t)4096 * 1024 * 2);
  u16* KROT = (u16*)alloc((size_t)4096 * 1024 * 2);
  u16* VT   = (u16*)alloc((size_t)4096 * 1024 * 2);
  u16* AOUT = (u16*)alloc((size_t)4096 * 1024 * 2);
  float* posq  = (float*)alloc(4096 * 4);
  float* vq    = (float*)alloc(4096 * 4);
  float* posk  = (float*)alloc(4096 * 4);
  float* kbias = (float*)alloc(4096 * 4);
  float* dtok  = (float*)alloc(4096 * 4);

  wtrans_kernel<<<dim3(16, 16), 256, 0, stream>>>(Wq, WqT, 1024, 1024);
  wtrans_kernel<<<dim3(32, 16), 256, 0, stream>>>(Wkv, WkvT, 1024, 2048);
  wtrans_kernel<<<dim3(16, 16), 256, 0, stream>>>(Wo, WoT, 1024, 1024);
  cvt_kernel<<<4096, 256, 0, stream>>>(q_states, QS, 4096 * 1024);
  cvt_kernel<<<4096, 256, 0, stream>>>(kv_states, KVS, 4096 * 1024);
  pos_seg_kernel<<<2, 256, 0, stream>>>(mq, nullptr, posq, vq, nullptr, 2048, 0);
  pos_seg_kernel<<<2, 256, 0, stream>>>(mkv, dists, posk, kbias, dtok, 2048, 1);

  gemm_kernel<0><<<dim3(8, 32), 256, 0, stream>>>(QS, WqT, bq, 4096, 1024, 1024,
                                                  posq, nullptr, QROT, nullptr, nullptr);
  gemm_kernel<1><<<dim3(16, 32), 256, 0, stream>>>(KVS, WkvT, bkv, 4096, 2048, 1024,
                                                   posk, dtok, KROT, VT, nullptr);
  attn_kernel<<<dim3(16, 16, 2), 256, 0, stream>>>(QROT, KROT, VT, kbias, vq, AOUT);
  gemm_kernel<2><<<dim3(8, 32), 256, 0, stream>>>(AOUT, WoT, bo, 4096, 1024, 1024,
                                                  nullptr, nullptr, nullptr, nullptr, out);
}